// Round 24
// baseline (100.575 us; speedup 1.0000x reference)
//
#include <hip/hip_runtime.h>

// ---------- types ----------
typedef float f32x4  __attribute__((ext_vector_type(4)));
typedef float f32x16 __attribute__((ext_vector_type(16)));
typedef short bh8    __attribute__((ext_vector_type(8)));   // 8 bf16 in 4 VGPRs
typedef unsigned int u32;

#define MFMA16(a, b, c) __builtin_amdgcn_mfma_f32_16x16x32_bf16(a, b, c, 0, 0, 0)
#define MFMA32(a, b, c) __builtin_amdgcn_mfma_f32_32x32x16_bf16(a, b, c, 0, 0, 0)

// dims
#define BB 2
#define SS 2048
#define DD 1024
#define HH 16
#define HDIM 64
#define TT (BB * SS)   // 4096

#define QSCALE 0.18033688011f   // log2(e)/8 : folds 1/sqrt(64) + exp->exp2

__device__ __forceinline__ unsigned short f2bf(float f) {
  unsigned u = __float_as_uint(f);
  u += 0x7fffu + ((u >> 16) & 1u);   // RNE
  return (unsigned short)(u >> 16);
}
__device__ __forceinline__ u32 cvtpk(float lo, float hi) {
  u32 r;
  asm("v_cvt_pk_bf16_f32 %0, %1, %2" : "=v"(r) : "v"(lo), "v"(hi));
  return r;
}
// gfx950 ISA: v_permlane32_swap_b32 vdst, vsrc: a[32:63] <-> b[0:31].
#define PLSWAP(a, b) \
  asm("v_permlane32_swap_b32 %0, %1" : "+v"(a), "+v"(b))

// async global->LDS, 16B per lane (wave-uniform LDS base, lane l -> base+16l)
__device__ __forceinline__ void gload_lds16(const void* gsrc, const void* ldst) {
  __builtin_amdgcn_global_load_lds(
      (const __attribute__((address_space(1))) unsigned int*)(unsigned long long)gsrc,
      (__attribute__((address_space(3))) unsigned int*)(unsigned int)(unsigned long long)ldst,
      16, 0, 0);
}

// ---------- fp32 -> bf16 convert: x + all 4 weights in ONE launch ----------
__global__ void cvt_all(const float* __restrict__ x,
                        const float* __restrict__ w0, const float* __restrict__ w1,
                        const float* __restrict__ w2, const float* __restrict__ w3,
                        unsigned short* __restrict__ xb,
                        unsigned short* __restrict__ wb) {
  const int b = blockIdx.x;
  const float* src;
  unsigned short* dst;
  int i;
  if (b < 2048) {
    src = x; dst = xb;
    i = b * 256 + threadIdx.x;
  } else {
    const int z = (b - 2048) >> 9;             // 0..3
    src = (z == 0) ? w0 : (z == 1) ? w1 : (z == 2) ? w2 : w3;
    dst = wb + (size_t)z * 1048576;
    i = ((b - 2048) & 511) * 256 + threadIdx.x;
  }
  const float4* s = (const float4*)src;
  float4 a = s[i * 2 + 0];
  float4 c = s[i * 2 + 1];
  bh8 v;
  v[0] = (short)f2bf(a.x); v[1] = (short)f2bf(a.y);
  v[2] = (short)f2bf(a.z); v[3] = (short)f2bf(a.w);
  v[4] = (short)f2bf(c.x); v[5] = (short)f2bf(c.y);
  v[6] = (short)f2bf(c.z); v[7] = (short)f2bf(c.w);
  *(bh8*)(dst + (size_t)i * 8) = v;
}

// ---------- QKV GEMM, T3 one-barrier double-buffered pipeline (R22 frozen) ----------
// NOTE: s_setprio is LOAD-BEARING here — removing it (R23) shifted codegen
// and exposed a latent timing sensitivity (absmax 3.8e-3). Do not remove.
__global__ __launch_bounds__(256, 4) void gemm128(
    const unsigned short* __restrict__ A,
    const unsigned short* __restrict__ Bw,
    const float* __restrict__ b0, const float* __restrict__ b1,
    const float* __restrict__ b2,
    unsigned short* __restrict__ Qw, unsigned short* __restrict__ Kw,
    unsigned short* __restrict__ Vtw) {
  __shared__ __attribute__((aligned(16))) unsigned short As[2][128 * 32];
  __shared__ __attribute__((aligned(16))) unsigned short Bs[2][128 * 32];

  const int tid = threadIdx.x, lane = tid & 63, wid = tid >> 6;
  const int c = lane & 15, g = lane >> 4;
  const int wr = wid >> 1, wc = wid & 1;
  const int m0 = blockIdx.x * 128, n0 = blockIdx.y * 128;

  const unsigned short* Ab = A + (size_t)(m0 + (lane >> 2)) * DD + (lane & 3) * 8;
  const unsigned short* Bb = Bw + (size_t)(n0 + (lane >> 2)) * DD + (lane & 3) * 8;
  const int rowb0 = wid * 32, rowb1 = wid * 32 + 16;   // wave-uniform rows

  f32x4 acc[4][4];
#pragma unroll
  for (int mi = 0; mi < 4; ++mi)
#pragma unroll
    for (int ni = 0; ni < 4; ++ni) acc[mi][ni] = (f32x4){0.f, 0.f, 0.f, 0.f};

  gload_lds16(Ab + (size_t)rowb0 * DD, &As[0][rowb0 * 32]);
  gload_lds16(Ab + (size_t)rowb1 * DD, &As[0][rowb1 * 32]);
  gload_lds16(Bb + (size_t)rowb0 * DD, &Bs[0][rowb0 * 32]);
  gload_lds16(Bb + (size_t)rowb1 * DD, &Bs[0][rowb1 * 32]);
  __syncthreads();   // vmcnt(0) drain: tile 0 visible

  const int NT = DD / 32;   // 32 K-steps
  for (int t = 0; t < NT; ++t) {
    const int cur = t & 1;
    if (t + 1 < NT) {
      const int k1 = (t + 1) * 32;
      gload_lds16(Ab + (size_t)rowb0 * DD + k1, &As[cur ^ 1][rowb0 * 32]);
      gload_lds16(Ab + (size_t)rowb1 * DD + k1, &As[cur ^ 1][rowb1 * 32]);
      gload_lds16(Bb + (size_t)rowb0 * DD + k1, &Bs[cur ^ 1][rowb0 * 32]);
      gload_lds16(Bb + (size_t)rowb1 * DD + k1, &Bs[cur ^ 1][rowb1 * 32]);
    }

    bh8 a[4], b[4];
#pragma unroll
    for (int mi = 0; mi < 4; ++mi)
      a[mi] = *(const bh8*)&As[cur][(wr * 64 + mi * 16 + c) * 32 + g * 8];
#pragma unroll
    for (int ni = 0; ni < 4; ++ni)
      b[ni] = *(const bh8*)&Bs[cur][(wc * 64 + ni * 16 + c) * 32 + g * 8];
    __builtin_amdgcn_s_setprio(1);
#pragma unroll
    for (int mi = 0; mi < 4; ++mi)
#pragma unroll
      for (int ni = 0; ni < 4; ++ni)
        acc[mi][ni] = MFMA16(a[mi], b[ni], acc[mi][ni]);
    __builtin_amdgcn_s_setprio(0);

    __syncthreads();   // retires reads of cur AND publishes tile t+1
  }

#pragma unroll
  for (int ni = 0; ni < 4; ++ni) {
    const int n = n0 + wc * 64 + ni * 16 + c;
    const int z = n >> 10, oo = n & 1023;
    const float bias = (z == 0 ? b0 : (z == 1 ? b1 : b2))[oo];
    const int h = oo >> 6, hd = oo & 63;
    if (z == 2) {
      // V: 4 consecutive s per (mi) -> 2 uint2 stores
#pragma unroll
      for (int mi = 0; mi < 4; ++mi) {
        const int mb = m0 + wr * 64 + mi * 16 + g * 4;
        const int bb = mb >> 11, s = mb & (SS - 1);
        uint2 v;
        v.x = cvtpk(acc[mi][ni][0] + bias, acc[mi][ni][1] + bias);
        v.y = cvtpk(acc[mi][ni][2] + bias, acc[mi][ni][3] + bias);
        *(uint2*)(Vtw + (((size_t)(bb * HH + h) * HDIM + hd) << 11) + s) = v;
      }
    } else {
      unsigned short* O = (z == 0) ? Qw : Kw;
      const float sc = (z == 0) ? QSCALE : 1.0f;
#pragma unroll
      for (int mi = 0; mi < 4; ++mi)
#pragma unroll
        for (int j = 0; j < 4; ++j) {
          const int m = m0 + wr * 64 + mi * 16 + g * 4 + j;
          const int bb = m >> 11, s = m & (SS - 1);
          O[(((size_t)(bb * HH + h) * SS + s) << 6) + hd] =
              f2bf((acc[mi][ni][j] + bias) * sc);
        }
    }
  }
}

// ---------- out-proj GEMM: 64x128 tile, 2 blocks/CU (R22 frozen) ----------
__global__ __launch_bounds__(256, 4) void gemm64(
    const unsigned short* __restrict__ A,
    const unsigned short* __restrict__ Bw,
    const float* __restrict__ b0, float* __restrict__ outf) {
  __shared__ __attribute__((aligned(16))) unsigned short As[2][64 * 32];
  __shared__ __attribute__((aligned(16))) unsigned short Bs[2][128 * 32];

  const int tid = threadIdx.x, lane = tid & 63, wid = tid >> 6;
  const int c = lane & 15, g = lane >> 4;
  const int wr = wid >> 1, wc = wid & 1;
  const int m0 = blockIdx.x * 64, n0 = blockIdx.y * 128;

  const unsigned short* Ab = A + (size_t)(m0 + (lane >> 2)) * DD + (lane & 3) * 8;
  const unsigned short* Bb = Bw + (size_t)(n0 + (lane >> 2)) * DD + (lane & 3) * 8;
  const int arow = wid * 16;
  const int brow0 = wid * 32, brow1 = wid * 32 + 16;

  f32x4 acc[2][4];
#pragma unroll
  for (int mi = 0; mi < 2; ++mi)
#pragma unroll
    for (int ni = 0; ni < 4; ++ni) acc[mi][ni] = (f32x4){0.f, 0.f, 0.f, 0.f};

  gload_lds16(Ab + (size_t)arow * DD, &As[0][arow * 32]);
  gload_lds16(Bb + (size_t)brow0 * DD, &Bs[0][brow0 * 32]);
  gload_lds16(Bb + (size_t)brow1 * DD, &Bs[0][brow1 * 32]);
  __syncthreads();

  const int NT = DD / 32;
  for (int t = 0; t < NT; ++t) {
    const int cur = t & 1;
    if (t + 1 < NT) {
      const int k1 = (t + 1) * 32;
      gload_lds16(Ab + (size_t)arow * DD + k1, &As[cur ^ 1][arow * 32]);
      gload_lds16(Bb + (size_t)brow0 * DD + k1, &Bs[cur ^ 1][brow0 * 32]);
      gload_lds16(Bb + (size_t)brow1 * DD + k1, &Bs[cur ^ 1][brow1 * 32]);
    }

    bh8 a[2], b[4];
#pragma unroll
    for (int mi = 0; mi < 2; ++mi)
      a[mi] = *(const bh8*)&As[cur][(wr * 32 + mi * 16 + c) * 32 + g * 8];
#pragma unroll
    for (int ni = 0; ni < 4; ++ni)
      b[ni] = *(const bh8*)&Bs[cur][(wc * 64 + ni * 16 + c) * 32 + g * 8];
    __builtin_amdgcn_s_setprio(1);
#pragma unroll
    for (int mi = 0; mi < 2; ++mi)
#pragma unroll
      for (int ni = 0; ni < 4; ++ni)
        acc[mi][ni] = MFMA16(a[mi], b[ni], acc[mi][ni]);
    __builtin_amdgcn_s_setprio(0);

    __syncthreads();
  }

#pragma unroll
  for (int ni = 0; ni < 4; ++ni) {
    const int n = n0 + wc * 64 + ni * 16 + c;
    const float bias = b0[n];
#pragma unroll
    for (int mi = 0; mi < 2; ++mi)
#pragma unroll
      for (int j = 0; j < 4; ++j) {
        const int m = m0 + wr * 32 + mi * 16 + g * 4 + j;
        outf[(size_t)m * DD + n] = acc[mi][ni][j] + bias;
      }
  }
}

// ---------- flash attention v10 (R22 frozen): padded [64][72], seq kvt ----------
__global__ __launch_bounds__(256, 3) void attn8(
    const unsigned short* __restrict__ Qw, const unsigned short* __restrict__ Kw,
    const unsigned short* __restrict__ Vtw, unsigned short* __restrict__ attnw) {
  __shared__ __attribute__((aligned(16))) unsigned short KT[2][64][72];
  __shared__ __attribute__((aligned(16))) unsigned short VT[2][64][72];

  const int f = blockIdx.x;
  const int work = (f & 7) * 64 + (f >> 3);   // bijective: 512 = 8*64
  const int bx = work & 15;                   // q-block (S/128)
  const int bh = work >> 4;                   // 0..31
  const int by = bh & 15, bz = bh >> 4;

  const int tid = threadIdx.x;
  const int lane = tid & 63, wid = tid >> 6;
  const int q = lane & 31, hi = lane >> 5;
  const unsigned short* Qb = Qw + (size_t)bh * SS * HDIM;
  const unsigned short* Kb = Kw + (size_t)bh * SS * HDIM;
  const unsigned short* Vb = Vtw + (size_t)bh * HDIM * SS;
  const int q0 = bx * 128 + wid * 32;

  bh8 qf[4];
#pragma unroll
  for (int ks = 0; ks < 4; ++ks)
    qf[ks] = *(const bh8*)(Qb + (size_t)(q0 + q) * HDIM + ks * 16 + hi * 8);

  f32x16 O0, O1;
#pragma unroll
  for (int r = 0; r < 16; ++r) { O0[r] = 0.f; O1[r] = 0.f; }
  float la[4] = {0.f, 0.f, 0.f, 0.f};

  const int srow = tid >> 2;
  const int scol = (tid & 3) * 16;
  const unsigned short* Ksrc = Kb + (size_t)srow * HDIM + scol;
  const unsigned short* Vsrc = Vb + (size_t)srow * SS + scol;

  bh8 kr0 = *(const bh8*)(Ksrc + 0), kr1 = *(const bh8*)(Ksrc + 8);
  bh8 vr0 = *(const bh8*)(Vsrc + 0), vr1 = *(const bh8*)(Vsrc + 8);
  *(bh8*)&KT[0][srow][scol] = kr0; *(bh8*)&KT[0][srow][scol + 8] = kr1;
  *(bh8*)&VT[0][srow][scol] = vr0; *(bh8*)&VT[0][srow][scol + 8] = vr1;
  kr0 = *(const bh8*)(Ksrc + 64 * HDIM); kr1 = *(const bh8*)(Ksrc + 64 * HDIM + 8);
  vr0 = *(const bh8*)(Vsrc + 64);        vr1 = *(const bh8*)(Vsrc + 64 + 8);

  const int NT = SS / 64;   // 32 tiles, full sequence
  for (int kt = 0; kt < NT; ++kt) {
    const int cur = kt & 1;
    __syncthreads();
    if (kt + 1 < NT) {
      *(bh8*)&KT[cur ^ 1][srow][scol] = kr0;
      *(bh8*)&KT[cur ^ 1][srow][scol + 8] = kr1;
      *(bh8*)&VT[cur ^ 1][srow][scol] = vr0;
      *(bh8*)&VT[cur ^ 1][srow][scol + 8] = vr1;
      if (kt + 2 < NT) {
        const size_t ko = (size_t)(kt + 2) * 64 * HDIM, vo = (size_t)(kt + 2) * 64;
        kr0 = *(const bh8*)(Ksrc + ko); kr1 = *(const bh8*)(Ksrc + ko + 8);
        vr0 = *(const bh8*)(Vsrc + vo); vr1 = *(const bh8*)(Vsrc + vo + 8);
      }
    }

#pragma unroll
    for (int kvt = 0; kvt < 2; ++kvt) {
      bh8 kf[4];
#pragma unroll
      for (int ks = 0; ks < 4; ++ks)
        kf[ks] = *(const bh8*)&KT[cur][kvt * 32 + q][ks * 16 + hi * 8];
      f32x16 a;
#pragma unroll
      for (int r = 0; r < 16; ++r) a[r] = 0.f;
      __builtin_amdgcn_s_setprio(1);
#pragma unroll
      for (int ks = 0; ks < 4; ++ks) a = MFMA32(kf[ks], qf[ks], a);
      __builtin_amdgcn_s_setprio(0);

      bh8 vf00 = *(const bh8*)&VT[cur][q][kvt * 32 + hi * 8];
      bh8 vf01 = *(const bh8*)&VT[cur][32 + q][kvt * 32 + hi * 8];
      bh8 vf10 = *(const bh8*)&VT[cur][q][kvt * 32 + 16 + hi * 8];
      bh8 vf11 = *(const bh8*)&VT[cur][32 + q][kvt * 32 + 16 + hi * 8];

      u32 w[8];
#pragma unroll
      for (int i = 0; i < 8; ++i) {
        float p0 = __builtin_amdgcn_exp2f(a[2 * i]);
        float p1 = __builtin_amdgcn_exp2f(a[2 * i + 1]);
        la[i & 3] += p0 + p1;
        w[i] = cvtpk(p0, p1);
      }
      PLSWAP(w[0], w[2]); PLSWAP(w[1], w[3]);
      PLSWAP(w[4], w[6]); PLSWAP(w[5], w[7]);

      union { u32 uw[4]; bh8 h; } pa0, pa1;
#pragma unroll
      for (int j = 0; j < 4; ++j) { pa0.uw[j] = w[j]; pa1.uw[j] = w[4 + j]; }
      __builtin_amdgcn_s_setprio(1);
      O0 = MFMA32(vf00, pa0.h, O0);
      O1 = MFMA32(vf01, pa0.h, O1);
      O0 = MFMA32(vf10, pa1.h, O0);
      O1 = MFMA32(vf11, pa1.h, O1);
      __builtin_amdgcn_s_setprio(0);
    }
  }

  // ---- epilogue: l row-total (cross-half once), normalized bf16 output ----
  float l = (la[0] + la[1]) + (la[2] + la[3]);
  {
    float xa = l, xb = l;
    asm("" : "+v"(xb));
    PLSWAP(xa, xb);
    l = xa + xb;
  }
  const float inv = 1.0f / l;
  unsigned short* orow =
      attnw + (size_t)(bz * SS + q0 + q) * DD + by * HDIM;
#pragma unroll
  for (int rq = 0; rq < 4; ++rq) {
    const int db0 = 8 * rq + 4 * hi;
    uint2 v0, v1;
    v0.x = cvtpk(O0[4 * rq + 0] * inv, O0[4 * rq + 1] * inv);
    v0.y = cvtpk(O0[4 * rq + 2] * inv, O0[4 * rq + 3] * inv);
    v1.x = cvtpk(O1[4 * rq + 0] * inv, O1[4 * rq + 1] * inv);
    v1.y = cvtpk(O1[4 * rq + 2] * inv, O1[4 * rq + 3] * inv);
    *(uint2*)(orow + db0) = v0;
    *(uint2*)(orow + 32 + db0) = v1;
  }
}

// ---------- launch ----------
extern "C" void kernel_launch(void* const* d_in, const int* in_sizes, int n_in,
                              void* d_out, int out_size, void* d_ws,
                              size_t ws_size, hipStream_t stream) {
  const float* x  = (const float*)d_in[0];
  const float* Wq = (const float*)d_in[1];
  const float* bq = (const float*)d_in[2];
  const float* Wk = (const float*)d_in[3];
  const float* bk = (const float*)d_in[4];
  const float* Wv = (const float*)d_in[5];
  const float* bv = (const float*)d_in[6];
  const float* Wo = (const float*)d_in[7];
  const float* bo = (const float*)d_in[8];
  float* out = (float*)d_out;

  unsigned short* ws = (unsigned short*)d_ws;
  unsigned short* xb    = ws;                    // 4M  [T,D]
  unsigned short* Wqb   = ws + 4194304;          // 1M x4 (Wq,Wk,Wv,Wo contiguous)
  unsigned short* Qw    = ws + 8388608;          // 4M  [bh][s][hd] (pre-scaled)
  unsigned short* Kw    = ws + 12582912;         // 4M  [bh][s][hd]
  unsigned short* Vtw   = ws + 16777216;         // 4M  [bh][hd][s]
  unsigned short* attnw = ws + 20971520;         // 4M  [T,D]

  cvt_all<<<dim3(4096), 256, 0, stream>>>(x, Wq, Wk, Wv, Wo, xb, Wqb);

  gemm128<<<dim3(TT / 128, 3072 / 128), 256, 0, stream>>>(
      xb, Wqb, bq, bk, bv, Qw, Kw, Vtw);

  attn8<<<dim3(512), 256, 0, stream>>>(Qw, Kw, Vtw, attnw);

  gemm64<<<dim3(TT / 64, DD / 128), 256, 0, stream>>>(
      attnw, Wqb + 3 * 1048576, bo, out);
}